// Round 1
// baseline (129.790 us; speedup 1.0000x reference)
//
#include <hip/hip_runtime.h>
#include <math.h>

#define B_SZ 1024
#define Z_DIM 512
#define A_DIM 8
#define AH 64
#define ZH 512
#define NNEG 99
#define INV_T 10.0f

typedef __attribute__((ext_vector_type(8))) short short8;   // 8 bf16 (16 B)
typedef __attribute__((ext_vector_type(4))) float f32x4;

// fp32 -> bf16 round-to-nearest-even (unbiased; rel err <= 2^-9)
__device__ __forceinline__ short bf16rn(float x) {
    unsigned u = __float_as_uint(x);
    u += 0x7fffu + ((u >> 16) & 1u);
    return (short)(u >> 16);
}
__device__ __forceinline__ void cvt8rn(float4 x0, float4 x1, short8& h) {
    h[0] = bf16rn(x0.x); h[1] = bf16rn(x0.y); h[2] = bf16rn(x0.z); h[3] = bf16rn(x0.w);
    h[4] = bf16rn(x1.x); h[5] = bf16rn(x1.y); h[6] = bf16rn(x1.z); h[7] = bf16rn(x1.w);
}

// XOR-swizzled 16B-unit index into a [64 rows][8 units] bf16 tile (no padding).
__device__ __forceinline__ int sw(int m, int kb) { return m * 8 + (kb ^ (m & 7)); }

// ---------------------------------------------------------------------------
// prep: blocks [0,72) transpose W1 [576][512] -> W1T [512][576];
//       blocks [72,88) compute ha = relu(actions@Wa+ba)  [1024][64];
//       block 0 resets cnt.
__global__ __launch_bounds__(256) void prep_kernel(
    const float* __restrict__ W1, const float* __restrict__ actions,
    const float* __restrict__ Wa, const float* __restrict__ ba,
    float* __restrict__ W1T, float* __restrict__ ha, unsigned* __restrict__ cnt)
{
    const int id = blockIdx.x, tid = threadIdx.x;
    if (id == 0 && tid == 0) atomicExch(cnt, 0u);
    if (id < 72) {
        __shared__ float L[64][68];
        int kt = id >> 3, nt = id & 7;
#pragma unroll
        for (int i = 0; i < 4; ++i) {
            int f = tid + i * 256;
            int r = f >> 4, c4 = (f & 15) << 2;
            *(float4*)&L[r][c4] = *(const float4*)&W1[(kt * 64 + r) * 512 + nt * 64 + c4];
        }
        __syncthreads();
#pragma unroll
        for (int i = 0; i < 4; ++i) {
            int f = tid + i * 256;
            int r = f >> 4, c4 = (f & 15) << 2;
            float4 o = {L[c4][r], L[c4 + 1][r], L[c4 + 2][r], L[c4 + 3][r]};
            *(float4*)&W1T[(nt * 64 + r) * 576 + kt * 64 + c4] = o;
        }
    } else if (id < 88) {
        __shared__ float sWa[A_DIM * 64];
        __shared__ float sba[64];
        __shared__ float sact[64][A_DIM];
        int j0 = (id - 72) * 64;
        for (int i = tid; i < A_DIM * 64; i += 256) sWa[i] = Wa[i];
        if (tid < 64) sba[tid] = ba[tid];
        for (int i = tid; i < 64 * A_DIM; i += 256) (&sact[0][0])[i] = actions[j0 * A_DIM + i];
        __syncthreads();
        int r = tid >> 2, c0 = (tid & 3) * 16;
        float o[16];
#pragma unroll
        for (int c = 0; c < 16; ++c) o[c] = sba[c0 + c];
#pragma unroll
        for (int k = 0; k < A_DIM; ++k) {
            float a = sact[r][k];
#pragma unroll
            for (int c = 0; c < 16; ++c) o[c] += a * sWa[k * 64 + c0 + c];
        }
#pragma unroll
        for (int c = 0; c < 16; c += 4) {
            float4 v4 = {fmaxf(o[c], 0.f), fmaxf(o[c + 1], 0.f),
                         fmaxf(o[c + 2], 0.f), fmaxf(o[c + 3], 0.f)};
            *(float4*)&ha[(j0 + r) * 64 + c0 + c] = v4;
        }
    }
}

// ---------------------------------------------------------------------------
// Uniform NT MFMA GEMM, 640 blocks, plain bf16 (RN conversion at staging):
//   seg0 [  0,256): sim = z_next @ z_next_hat^T [1024x1024 K=512]
//   seg1 [256,384): u   = z @ W1T[:, :512]^T+b1 [1024x512  K=512]
//   seg2 [384,512): v   = z_next @ W2^T         [1024x512  K=512]
//   seg3 [512,640): g   = ha @ W1T[:,512:]^T    [1024x512  K=64]
__global__ __launch_bounds__(256) void mm_kernel(
    const float* __restrict__ z, const float* __restrict__ z_next,
    const float* __restrict__ z_next_hat, const float* __restrict__ W1T,
    const float* __restrict__ b1, const float* __restrict__ W2,
    const float* __restrict__ ha,
    float* __restrict__ sim, float* __restrict__ u, float* __restrict__ v,
    float* __restrict__ g)
{
    __shared__ short Ah[4096], Bh[4096];   // 16 KB

    const int id = blockIdx.x;
    const int tid = threadIdx.x;

    const float* Aop; const float* Bop; const float* bias = nullptr;
    float* C; int N, K, lda, ldb, bm0, bn0;
    if (id < 256) {
        int t = id; bn0 = (t & 15) * 64; bm0 = (t >> 4) * 64;
        Aop = z_next; lda = 512; Bop = z_next_hat; ldb = 512;
        C = sim; N = 1024; K = 512;
    } else if (id < 384) {
        int t = id - 256; bn0 = (t & 7) * 64; bm0 = (t >> 3) * 64;
        Aop = z; lda = 512; Bop = W1T; ldb = 576;
        C = u; N = 512; K = 512; bias = b1;
    } else if (id < 512) {
        int t = id - 384; bn0 = (t & 7) * 64; bm0 = (t >> 3) * 64;
        Aop = z_next; lda = 512; Bop = W2; ldb = 512;
        C = v; N = 512; K = 512;
    } else {
        int t = id - 512; bn0 = (t & 7) * 64; bm0 = (t >> 3) * 64;
        Aop = ha; lda = 64; Bop = W1T + 512; ldb = 576;
        C = g; N = 512; K = 64;
    }

    const int lane = tid & 63, wv = tid >> 6;
    const int lm = lane & 15, lq = lane >> 4;
    const int wm = (wv >> 1) * 32, wn = (wv & 1) * 32;
    const int sr = tid >> 2, sq = tid & 3;     // staging: row, 16-float quarter
    short8* Ah8 = (short8*)Ah; short8* Bh8 = (short8*)Bh;
    f32x4 acc[2][2] = {};

    for (int k0 = 0; k0 < K; k0 += 64) {
        {   // A: 16 consecutive floats of row sr -> units 2sq, 2sq+1
            const float* base = &Aop[(bm0 + sr) * lda + k0 + sq * 16];
            float4 x0 = *(const float4*)(base + 0), x1 = *(const float4*)(base + 4);
            float4 x2 = *(const float4*)(base + 8), x3 = *(const float4*)(base + 12);
            short8 h;
            cvt8rn(x0, x1, h); Ah8[sw(sr, 2 * sq)] = h;
            cvt8rn(x2, x3, h); Ah8[sw(sr, 2 * sq + 1)] = h;
        }
        {   // B: same, NT layout
            const float* base = &Bop[(bn0 + sr) * ldb + k0 + sq * 16];
            float4 x0 = *(const float4*)(base + 0), x1 = *(const float4*)(base + 4);
            float4 x2 = *(const float4*)(base + 8), x3 = *(const float4*)(base + 12);
            short8 h;
            cvt8rn(x0, x1, h); Bh8[sw(sr, 2 * sq)] = h;
            cvt8rn(x2, x3, h); Bh8[sw(sr, 2 * sq + 1)] = h;
        }
        __syncthreads();
#pragma unroll
        for (int kk = 0; kk < 64; kk += 32) {
            int kbi = (kk >> 3) + lq;
            short8 ah[2], bh[2];
#pragma unroll
            for (int i = 0; i < 2; ++i) {
                ah[i] = Ah8[sw(wm + i * 16 + lm, kbi)];
                bh[i] = Bh8[sw(wn + i * 16 + lm, kbi)];
            }
#pragma unroll
            for (int i = 0; i < 2; ++i)
#pragma unroll
                for (int j = 0; j < 2; ++j)
                    acc[i][j] = __builtin_amdgcn_mfma_f32_16x16x32_bf16(ah[i], bh[j], acc[i][j], 0, 0, 0);
        }
        __syncthreads();
    }
    // epilogue: C layout col=lane&15, row=(lane>>4)*4+reg
#pragma unroll
    for (int i = 0; i < 2; ++i)
#pragma unroll
        for (int j = 0; j < 2; ++j) {
            int n = bn0 + wn + j * 16 + lm;
            float bb = bias ? bias[n] : 0.0f;
#pragma unroll
            for (int r = 0; r < 4; ++r) {
                int m = bm0 + wm + i * 16 + lq * 4 + r;
                C[m * N + n] = acc[i][j][r] + bb;
            }
        }
}

// ---------------------------------------------------------------------------
// row2 v3: 1024 blocks x 256 threads, ONE row per block (4x the occupancy of
// the previous 256-block version, which sat at 8.9% occupancy / 4% HBM —
// pure latency-bound). The 99 negative dot products are split across the 4
// waves (25/25/25/24 contiguous), each wave running 8 independent register
// ILP chains with DIRECT global loads of g (g is 2 MB, L2-resident — LDS
// staging was pure overhead, and this drops the per-iteration barriers).
// Phase 2 softmax/rank uses all 256 threads (4 sim entries each) with a
// two-stage shfl+LDS block reduction. Last block (cnt==1023) finalizes.
__global__ __launch_bounds__(256) void row2_kernel(
    const float* __restrict__ sim, const float* __restrict__ u,
    const float* __restrict__ v, const float* __restrict__ g,
    const float* __restrict__ z, const float* __restrict__ z_next,
    const float* __restrict__ b2,
    float* __restrict__ pw, unsigned* __restrict__ cnt, float* __restrict__ out)
{
    const int b = blockIdx.x;
    const int tid = threadIdx.x;
    const int w = tid >> 6, lane = tid & 63;
    __shared__ float rn[100];      // c0 + neg dot, indexed by s-1
    __shared__ float sred[12];     // [0:4) max, [4:8) expsum, [8:12) count
    __shared__ float red[256];
    __shared__ int sdone;

    // per-lane 8-float slices of u[b], v[b]
    float4 ua = *(const float4*)&u[b * 512 + lane * 4];
    float4 ub = *(const float4*)&u[b * 512 + 256 + lane * 4];
    float4 va = *(const float4*)&v[b * 512 + lane * 4];
    float4 vb = *(const float4*)&v[b * 512 + 256 + lane * 4];

    // c0 = (z[b]+b2) . z_next[b]   (computed redundantly by each wave; cached)
    float p;
    {
        float4 za = *(const float4*)&z[b * 512 + lane * 4];
        float4 zb = *(const float4*)&z[b * 512 + 256 + lane * 4];
        float4 na = *(const float4*)&z_next[b * 512 + lane * 4];
        float4 nb = *(const float4*)&z_next[b * 512 + 256 + lane * 4];
        float4 ca = *(const float4*)&b2[lane * 4];
        float4 cb = *(const float4*)&b2[256 + lane * 4];
        p  = (za.x + ca.x) * na.x + (za.y + ca.y) * na.y + (za.z + ca.z) * na.z + (za.w + ca.w) * na.w;
        p += (zb.x + cb.x) * nb.x + (zb.y + cb.y) * nb.y + (zb.z + cb.z) * nb.z + (zb.w + cb.w) * nb.w;
    }
    for (int off = 32; off; off >>= 1) p += __shfl_down(p, off);
    const float c0 = __shfl(p, 0);

    // -------- phase 1: negatives. wave w owns s-1 in [w*25, w*25+cntw) -----
    const int base = w * 25;
    const int cntw = (w < 3) ? 25 : 24;
#pragma unroll
    for (int rr = 0; rr < 4; ++rr) {
        float4 ga[8], gb[8];
        float t[8];
#pragma unroll
        for (int c = 0; c < 8; ++c) {
            int q = rr * 8 + c;
            if (q < cntw) {                       // wave-uniform predicate
                int j = (b + 1 + base + q) & (B_SZ - 1);
                ga[c] = *(const float4*)&g[j * 512 + lane * 4];
                gb[c] = *(const float4*)&g[j * 512 + 256 + lane * 4];
            }
        }
#pragma unroll
        for (int c = 0; c < 8; ++c) {
            float s = 0.0f;
            s += fmaxf(ua.x + ga[c].x, 0.0f) * va.x;
            s += fmaxf(ua.y + ga[c].y, 0.0f) * va.y;
            s += fmaxf(ua.z + ga[c].z, 0.0f) * va.z;
            s += fmaxf(ua.w + ga[c].w, 0.0f) * va.w;
            s += fmaxf(ub.x + gb[c].x, 0.0f) * vb.x;
            s += fmaxf(ub.y + gb[c].y, 0.0f) * vb.y;
            s += fmaxf(ub.z + gb[c].z, 0.0f) * vb.z;
            s += fmaxf(ub.w + gb[c].w, 0.0f) * vb.w;
            t[c] = s;
        }
        for (int off = 32; off; off >>= 1) {
#pragma unroll
            for (int c = 0; c < 8; ++c) t[c] += __shfl_down(t[c], off);
        }
        if (lane == 0) {
#pragma unroll
            for (int c = 0; c < 8; ++c) {
                int q = rr * 8 + c;
                if (q < cntw) rn[base + q] = c0 + t[c];
            }
        }
    }
    __syncthreads();

    // -------- phase 2: softmax + rank, 256 threads x 4 sim entries --------
    float4 s4 = *(const float4*)&sim[b * 1024 + tid * 4];
    float neg = (tid < NNEG) ? rn[tid] : -3.4e38f;
    float diag = sim[b * 1024 + b];

    float m = fmaxf(fmaxf(s4.x, s4.y), fmaxf(s4.z, s4.w));
    m = fmaxf(m, neg);
    for (int off = 32; off; off >>= 1) m = fmaxf(m, __shfl_xor(m, off));
    if (lane == 0) sred[w] = m;
    __syncthreads();
    m = fmaxf(fmaxf(sred[0], sred[1]), fmaxf(sred[2], sred[3]));

    float es = 0.0f; int ck = 0;
    {
        float xs[4] = {s4.x, s4.y, s4.z, s4.w};
#pragma unroll
        for (int c = 0; c < 4; ++c) {
            int j = tid * 4 + c;
            float x = xs[c];
            es += __expf((x - m) * INV_T);
            if (x > diag) ck++;
            else if (j < b && x == diag) ck++;   // tie-break: lower index wins
        }
    }
    if (tid < NNEG) {
        es += __expf((neg - m) * INV_T);
        if (neg > diag) ck++;
    }
    float ckf = (float)ck;
    for (int off = 32; off; off >>= 1) {
        es += __shfl_down(es, off);
        ckf += __shfl_down(ckf, off);
    }
    if (lane == 0) { sred[4 + w] = es; sred[8 + w] = ckf; }
    __syncthreads();
    if (tid == 0) {
        float est = sred[4] + sred[5] + sred[6] + sred[7];
        int ckt = (int)(sred[8] + sred[9] + sred[10] + sred[11]);
        pw[b * 4 + 0] = (m - diag) * INV_T + logf(est);
        pw[b * 4 + 1] = (ckt < 1) ? 1.0f : 0.0f;
        pw[b * 4 + 2] = (ckt < 3) ? 1.0f : 0.0f;
        pw[b * 4 + 3] = (ckt < 10) ? 1.0f : 0.0f;
        __threadfence();
        unsigned old = atomicAdd(cnt, 1u);
        sdone = (old == 1023u) ? 1 : 0;
    }
    __syncthreads();
    if (sdone) {
        __threadfence();
        int c = tid & 3;
        float s = 0.0f;
        for (int r = tid >> 2; r < 1024; r += 64) s += pw[r * 4 + c];
        red[tid] = s;
        __syncthreads();
        if (tid < 4) {
            float t = 0.0f;
            for (int q = 0; q < 64; ++q) t += red[tid + q * 4];
            out[tid] = t * (1.0f / (float)B_SZ);
        }
    }
}

// ---------------------------------------------------------------------------
extern "C" void kernel_launch(void* const* d_in, const int* in_sizes, int n_in,
                              void* d_out, int out_size, void* d_ws, size_t ws_size,
                              hipStream_t stream) {
    const float* z          = (const float*)d_in[0];
    const float* z_next     = (const float*)d_in[1];
    const float* z_next_hat = (const float*)d_in[2];
    const float* actions    = (const float*)d_in[3];
    const float* Wa         = (const float*)d_in[4];
    const float* ba         = (const float*)d_in[5];
    const float* W1         = (const float*)d_in[6];
    const float* b1         = (const float*)d_in[7];
    const float* W2         = (const float*)d_in[8];
    const float* b2         = (const float*)d_in[9];
    float* out = (float*)d_out;

    float* ws   = (float*)d_ws;
    float* sim  = ws;                          // 1024*1024
    float* u    = sim + B_SZ * B_SZ;           // 1024*512
    float* v    = u + B_SZ * ZH;               // 1024*512
    float* g    = v + B_SZ * ZH;               // 1024*512
    float* W1T  = g + B_SZ * ZH;               // 512*576
    float* ha   = W1T + 512 * 576;             // 1024*64
    float* pw   = ha + B_SZ * AH;              // 1024*4
    unsigned* cnt = (unsigned*)(pw + B_SZ * 4);

    prep_kernel<<<88, 256, 0, stream>>>(W1, actions, Wa, ba, W1T, ha, cnt);
    mm_kernel<<<640, 256, 0, stream>>>(z, z_next, z_next_hat, W1T, b1, W2, ha,
                                       sim, u, v, g);
    row2_kernel<<<1024, 256, 0, stream>>>(sim, u, v, g, z, z_next, b2, pw, cnt, out);
}

// Round 3
// 127.562 us; speedup vs baseline: 1.0175x; 1.0175x over previous
//
#include <hip/hip_runtime.h>
#include <math.h>

#define B_SZ 1024
#define Z_DIM 512
#define A_DIM 8
#define AH 64
#define ZH 512
#define NNEG 99
#define INV_T 10.0f

typedef __attribute__((ext_vector_type(8))) short short8;   // 8 bf16 (16 B)
typedef __attribute__((ext_vector_type(4))) float f32x4;

// fp32 -> bf16 round-to-nearest-even (unbiased; rel err <= 2^-9)
__device__ __forceinline__ short bf16rn(float x) {
    unsigned u = __float_as_uint(x);
    u += 0x7fffu + ((u >> 16) & 1u);
    return (short)(u >> 16);
}
__device__ __forceinline__ void cvt8rn(float4 x0, float4 x1, short8& h) {
    h[0] = bf16rn(x0.x); h[1] = bf16rn(x0.y); h[2] = bf16rn(x0.z); h[3] = bf16rn(x0.w);
    h[4] = bf16rn(x1.x); h[5] = bf16rn(x1.y); h[6] = bf16rn(x1.z); h[7] = bf16rn(x1.w);
}

// XOR-swizzled 16B-unit index into a [64 rows][8 units] bf16 tile (no padding).
__device__ __forceinline__ int sw(int m, int kb) { return m * 8 + (kb ^ (m & 7)); }

// ---------------------------------------------------------------------------
// prep: blocks [0,72) transpose W1 [576][512] -> W1T [512][576];
//       blocks [72,88) compute ha = relu(actions@Wa+ba)  [1024][64];
//       block 0 resets cnt.
__global__ __launch_bounds__(256) void prep_kernel(
    const float* __restrict__ W1, const float* __restrict__ actions,
    const float* __restrict__ Wa, const float* __restrict__ ba,
    float* __restrict__ W1T, float* __restrict__ ha, unsigned* __restrict__ cnt)
{
    const int id = blockIdx.x, tid = threadIdx.x;
    if (id == 0 && tid == 0) atomicExch(cnt, 0u);
    if (id < 72) {
        __shared__ float L[64][68];
        int kt = id >> 3, nt = id & 7;
#pragma unroll
        for (int i = 0; i < 4; ++i) {
            int f = tid + i * 256;
            int r = f >> 4, c4 = (f & 15) << 2;
            *(float4*)&L[r][c4] = *(const float4*)&W1[(kt * 64 + r) * 512 + nt * 64 + c4];
        }
        __syncthreads();
#pragma unroll
        for (int i = 0; i < 4; ++i) {
            int f = tid + i * 256;
            int r = f >> 4, c4 = (f & 15) << 2;
            float4 o = {L[c4][r], L[c4 + 1][r], L[c4 + 2][r], L[c4 + 3][r]};
            *(float4*)&W1T[(nt * 64 + r) * 576 + kt * 64 + c4] = o;
        }
    } else if (id < 88) {
        __shared__ float sWa[A_DIM * 64];
        __shared__ float sba[64];
        __shared__ float sact[64][A_DIM];
        int j0 = (id - 72) * 64;
        for (int i = tid; i < A_DIM * 64; i += 256) sWa[i] = Wa[i];
        if (tid < 64) sba[tid] = ba[tid];
        for (int i = tid; i < 64 * A_DIM; i += 256) (&sact[0][0])[i] = actions[j0 * A_DIM + i];
        __syncthreads();
        int r = tid >> 2, c0 = (tid & 3) * 16;
        float o[16];
#pragma unroll
        for (int c = 0; c < 16; ++c) o[c] = sba[c0 + c];
#pragma unroll
        for (int k = 0; k < A_DIM; ++k) {
            float a = sact[r][k];
#pragma unroll
            for (int c = 0; c < 16; ++c) o[c] += a * sWa[k * 64 + c0 + c];
        }
#pragma unroll
        for (int c = 0; c < 16; c += 4) {
            float4 v4 = {fmaxf(o[c], 0.f), fmaxf(o[c + 1], 0.f),
                         fmaxf(o[c + 2], 0.f), fmaxf(o[c + 3], 0.f)};
            *(float4*)&ha[(j0 + r) * 64 + c0 + c] = v4;
        }
    }
}

// ---------------------------------------------------------------------------
// Uniform NT MFMA GEMM, 640 blocks, plain bf16 (RN conversion at staging):
//   seg0 [  0,256): sim = z_next @ z_next_hat^T [1024x1024 K=512]
//   seg1 [256,384): u   = z @ W1T[:, :512]^T+b1 [1024x512  K=512]
//   seg2 [384,512): v   = z_next @ W2^T         [1024x512  K=512]
//   seg3 [512,640): g   = ha @ W1T[:,512:]^T    [1024x512  K=64]
__global__ __launch_bounds__(256) void mm_kernel(
    const float* __restrict__ z, const float* __restrict__ z_next,
    const float* __restrict__ z_next_hat, const float* __restrict__ W1T,
    const float* __restrict__ b1, const float* __restrict__ W2,
    const float* __restrict__ ha,
    float* __restrict__ sim, float* __restrict__ u, float* __restrict__ v,
    float* __restrict__ g)
{
    __shared__ short Ah[4096], Bh[4096];   // 16 KB

    const int id = blockIdx.x;
    const int tid = threadIdx.x;

    const float* Aop; const float* Bop; const float* bias = nullptr;
    float* C; int N, K, lda, ldb, bm0, bn0;
    if (id < 256) {
        int t = id; bn0 = (t & 15) * 64; bm0 = (t >> 4) * 64;
        Aop = z_next; lda = 512; Bop = z_next_hat; ldb = 512;
        C = sim; N = 1024; K = 512;
    } else if (id < 384) {
        int t = id - 256; bn0 = (t & 7) * 64; bm0 = (t >> 3) * 64;
        Aop = z; lda = 512; Bop = W1T; ldb = 576;
        C = u; N = 512; K = 512; bias = b1;
    } else if (id < 512) {
        int t = id - 384; bn0 = (t & 7) * 64; bm0 = (t >> 3) * 64;
        Aop = z_next; lda = 512; Bop = W2; ldb = 512;
        C = v; N = 512; K = 512;
    } else {
        int t = id - 512; bn0 = (t & 7) * 64; bm0 = (t >> 3) * 64;
        Aop = ha; lda = 64; Bop = W1T + 512; ldb = 576;
        C = g; N = 512; K = 64;
    }

    const int lane = tid & 63, wv = tid >> 6;
    const int lm = lane & 15, lq = lane >> 4;
    const int wm = (wv >> 1) * 32, wn = (wv & 1) * 32;
    const int sr = tid >> 2, sq = tid & 3;     // staging: row, 16-float quarter
    short8* Ah8 = (short8*)Ah; short8* Bh8 = (short8*)Bh;
    f32x4 acc[2][2] = {};

    for (int k0 = 0; k0 < K; k0 += 64) {
        {   // A: 16 consecutive floats of row sr -> units 2sq, 2sq+1
            const float* base = &Aop[(bm0 + sr) * lda + k0 + sq * 16];
            float4 x0 = *(const float4*)(base + 0), x1 = *(const float4*)(base + 4);
            float4 x2 = *(const float4*)(base + 8), x3 = *(const float4*)(base + 12);
            short8 h;
            cvt8rn(x0, x1, h); Ah8[sw(sr, 2 * sq)] = h;
            cvt8rn(x2, x3, h); Ah8[sw(sr, 2 * sq + 1)] = h;
        }
        {   // B: same, NT layout
            const float* base = &Bop[(bn0 + sr) * ldb + k0 + sq * 16];
            float4 x0 = *(const float4*)(base + 0), x1 = *(const float4*)(base + 4);
            float4 x2 = *(const float4*)(base + 8), x3 = *(const float4*)(base + 12);
            short8 h;
            cvt8rn(x0, x1, h); Bh8[sw(sr, 2 * sq)] = h;
            cvt8rn(x2, x3, h); Bh8[sw(sr, 2 * sq + 1)] = h;
        }
        __syncthreads();
#pragma unroll
        for (int kk = 0; kk < 64; kk += 32) {
            int kbi = (kk >> 3) + lq;
            short8 ah[2], bh[2];
#pragma unroll
            for (int i = 0; i < 2; ++i) {
                ah[i] = Ah8[sw(wm + i * 16 + lm, kbi)];
                bh[i] = Bh8[sw(wn + i * 16 + lm, kbi)];
            }
#pragma unroll
            for (int i = 0; i < 2; ++i)
#pragma unroll
                for (int j = 0; j < 2; ++j)
                    acc[i][j] = __builtin_amdgcn_mfma_f32_16x16x32_bf16(ah[i], bh[j], acc[i][j], 0, 0, 0);
        }
        __syncthreads();
    }
    // epilogue: C layout col=lane&15, row=(lane>>4)*4+reg
#pragma unroll
    for (int i = 0; i < 2; ++i)
#pragma unroll
        for (int j = 0; j < 2; ++j) {
            int n = bn0 + wn + j * 16 + lm;
            float bb = bias ? bias[n] : 0.0f;
#pragma unroll
            for (int r = 0; r < 4; ++r) {
                int m = bm0 + wm + i * 16 + lq * 4 + r;
                C[m * N + n] = acc[i][j][r] + bb;
            }
        }
}

// ---------------------------------------------------------------------------
// row2 v4 (resubmit — round-2 bench was an infra failure, no data): 1024
// blocks x 256 threads, one row per block.
// Round-1 evidence: duration invariant to 4x concurrency (43 us at both 256
// and 1024 blocks, VALUBusy ~12%, HBM 4%) => per-block SERIAL latency chain.
// VGPR_Count=60 showed the compiler re-serialized the g-row loads (the 8-row
// batch alone needs 64 VGPRs).  Fix: __launch_bounds__(256,2) opens the VGPR
// budget to ~256; two full 8-row register buffers (32 float4 loads) stay in
// flight, processed as chunks k = w, w+4, w+8 (+3-row tail on wave 0) with
// next-chunk loads issued before the current chunk's shuffle-reduce.
// Serial latency hops per wave: ~25 -> ~3.  Phase-2 inputs (sim row slice,
// diag) issue at the top of the kernel so their cold-L2 latency hides under
// phase 1.
#define LOADC(GA, GB, kk) { \
    const int q0_ = (kk) * 8; \
    _Pragma("unroll") \
    for (int c_ = 0; c_ < 8; ++c_) { \
        int j_ = (b + 1 + q0_ + c_) & (B_SZ - 1); \
        GA[c_] = *(const float4*)&g[j_ * 512 + lane * 4]; \
        GB[c_] = *(const float4*)&g[j_ * 512 + 256 + lane * 4]; \
    } }

#define LOADC3(GA, GB) { \
    _Pragma("unroll") \
    for (int c_ = 0; c_ < 3; ++c_) { \
        int j_ = (b + 97 + c_) & (B_SZ - 1); \
        GA[c_] = *(const float4*)&g[j_ * 512 + lane * 4]; \
        GB[c_] = *(const float4*)&g[j_ * 512 + 256 + lane * 4]; \
    } }

#define DOTC(T, GA, GB, NC) { \
    _Pragma("unroll") \
    for (int c_ = 0; c_ < (NC); ++c_) { \
        float s_ = 0.0f; \
        s_ += fmaxf(ua.x + GA[c_].x, 0.0f) * va.x; \
        s_ += fmaxf(ua.y + GA[c_].y, 0.0f) * va.y; \
        s_ += fmaxf(ua.z + GA[c_].z, 0.0f) * va.z; \
        s_ += fmaxf(ua.w + GA[c_].w, 0.0f) * va.w; \
        s_ += fmaxf(ub.x + GB[c_].x, 0.0f) * vb.x; \
        s_ += fmaxf(ub.y + GB[c_].y, 0.0f) * vb.y; \
        s_ += fmaxf(ub.z + GB[c_].z, 0.0f) * vb.z; \
        s_ += fmaxf(ub.w + GB[c_].w, 0.0f) * vb.w; \
        T[c_] = s_; \
    } }

#define REDST(T, kk, NC) { \
    for (int off_ = 32; off_; off_ >>= 1) { \
        _Pragma("unroll") \
        for (int c_ = 0; c_ < (NC); ++c_) T[c_] += __shfl_down(T[c_], off_); \
    } \
    if (lane == 0) { \
        _Pragma("unroll") \
        for (int c_ = 0; c_ < (NC); ++c_) rn[(kk) * 8 + c_] = c0 + T[c_]; \
    } }

__global__ __launch_bounds__(256, 2) void row2_kernel(
    const float* __restrict__ sim, const float* __restrict__ u,
    const float* __restrict__ v, const float* __restrict__ g,
    const float* __restrict__ z, const float* __restrict__ z_next,
    const float* __restrict__ b2,
    float* __restrict__ pw, unsigned* __restrict__ cnt, float* __restrict__ out)
{
    const int b = blockIdx.x;
    const int tid = threadIdx.x;
    const int w = tid >> 6, lane = tid & 63;
    __shared__ float rn[104];      // c0 + neg dot, indexed by s-1
    __shared__ float sred[12];     // [0:4) max, [4:8) expsum, [8:12) count
    __shared__ float red[256];
    __shared__ int sdone;

    // issue ALL phase-0/phase-2 input loads up front (latency hides in phase 1)
    float4 ua = *(const float4*)&u[b * 512 + lane * 4];
    float4 ub = *(const float4*)&u[b * 512 + 256 + lane * 4];
    float4 va = *(const float4*)&v[b * 512 + lane * 4];
    float4 vb = *(const float4*)&v[b * 512 + 256 + lane * 4];
    float4 s4 = *(const float4*)&sim[b * 1024 + tid * 4];
    float diag = sim[b * 1024 + b];

    // c0 = (z[b]+b2) . z_next[b]   (computed redundantly by each wave)
    float p;
    {
        float4 za = *(const float4*)&z[b * 512 + lane * 4];
        float4 zb = *(const float4*)&z[b * 512 + 256 + lane * 4];
        float4 na = *(const float4*)&z_next[b * 512 + lane * 4];
        float4 nb = *(const float4*)&z_next[b * 512 + 256 + lane * 4];
        float4 ca = *(const float4*)&b2[lane * 4];
        float4 cb = *(const float4*)&b2[256 + lane * 4];
        p  = (za.x + ca.x) * na.x + (za.y + ca.y) * na.y + (za.z + ca.z) * na.z + (za.w + ca.w) * na.w;
        p += (zb.x + cb.x) * nb.x + (zb.y + cb.y) * nb.y + (zb.z + cb.z) * nb.z + (zb.w + cb.w) * nb.w;
    }
    for (int off = 32; off; off >>= 1) p += __shfl_down(p, off);
    const float c0 = __shfl(p, 0);

    // -------- phase 1: negatives, chunks k0=w, k1=w+4, k2=w+8, tail on w0 --
    {
        const int k0 = w, k1 = w + 4, k2 = w + 8;
        float4 gaA[8], gbA[8], gaB[8], gbB[8];
        float tA[8], tB[8];

        LOADC(gaA, gbA, k0);            // 16 loads in flight
        LOADC(gaB, gbB, k1);            // 32 loads in flight
        DOTC(tA, gaA, gbA, 8);          // waits only on buffer A
        LOADC(gaA, gbA, k2);            // refill A while reducing
        REDST(tA, k0, 8);
        DOTC(tB, gaB, gbB, 8);
        if (w == 0) LOADC3(gaB, gbB);   // tail chunk 12 (rows 96..98)
        REDST(tB, k1, 8);
        DOTC(tA, gaA, gbA, 8);
        REDST(tA, k2, 8);
        if (w == 0) {
            DOTC(tB, gaB, gbB, 3);
            REDST(tB, 12, 3);
        }
    }
    __syncthreads();

    // -------- phase 2: softmax + rank, 256 threads x 4 sim entries --------
    float neg = (tid < NNEG) ? rn[tid] : -3.4e38f;

    float m = fmaxf(fmaxf(s4.x, s4.y), fmaxf(s4.z, s4.w));
    m = fmaxf(m, neg);
    for (int off = 32; off; off >>= 1) m = fmaxf(m, __shfl_xor(m, off));
    if (lane == 0) sred[w] = m;
    __syncthreads();
    m = fmaxf(fmaxf(sred[0], sred[1]), fmaxf(sred[2], sred[3]));

    float es = 0.0f; int ck = 0;
    {
        float xs[4] = {s4.x, s4.y, s4.z, s4.w};
#pragma unroll
        for (int c = 0; c < 4; ++c) {
            int j = tid * 4 + c;
            float x = xs[c];
            es += __expf((x - m) * INV_T);
            if (x > diag) ck++;
            else if (j < b && x == diag) ck++;   // tie-break: lower index wins
        }
    }
    if (tid < NNEG) {
        es += __expf((neg - m) * INV_T);
        if (neg > diag) ck++;
    }
    float ckf = (float)ck;
    for (int off = 32; off; off >>= 1) {
        es += __shfl_down(es, off);
        ckf += __shfl_down(ckf, off);
    }
    if (lane == 0) { sred[4 + w] = es; sred[8 + w] = ckf; }
    __syncthreads();
    if (tid == 0) {
        float est = sred[4] + sred[5] + sred[6] + sred[7];
        int ckt = (int)(sred[8] + sred[9] + sred[10] + sred[11]);
        pw[b * 4 + 0] = (m - diag) * INV_T + logf(est);
        pw[b * 4 + 1] = (ckt < 1) ? 1.0f : 0.0f;
        pw[b * 4 + 2] = (ckt < 3) ? 1.0f : 0.0f;
        pw[b * 4 + 3] = (ckt < 10) ? 1.0f : 0.0f;
        __threadfence();
        unsigned old = atomicAdd(cnt, 1u);
        sdone = (old == 1023u) ? 1 : 0;
    }
    __syncthreads();
    if (sdone) {
        __threadfence();
        int c = tid & 3;
        float s = 0.0f;
        for (int r = tid >> 2; r < 1024; r += 64) s += pw[r * 4 + c];
        red[tid] = s;
        __syncthreads();
        if (tid < 4) {
            float t = 0.0f;
            for (int q = 0; q < 64; ++q) t += red[tid + q * 4];
            out[tid] = t * (1.0f / (float)B_SZ);
        }
    }
}

// ---------------------------------------------------------------------------
extern "C" void kernel_launch(void* const* d_in, const int* in_sizes, int n_in,
                              void* d_out, int out_size, void* d_ws, size_t ws_size,
                              hipStream_t stream) {
    const float* z          = (const float*)d_in[0];
    const float* z_next     = (const float*)d_in[1];
    const float* z_next_hat = (const float*)d_in[2];
    const float* actions    = (const float*)d_in[3];
    const float* Wa         = (const float*)d_in[4];
    const float* ba         = (const float*)d_in[5];
    const float* W1         = (const float*)d_in[6];
    const float* b1         = (const float*)d_in[7];
    const float* W2         = (const float*)d_in[8];
    const float* b2         = (const float*)d_in[9];
    float* out = (float*)d_out;

    float* ws   = (float*)d_ws;
    float* sim  = ws;                          // 1024*1024
    float* u    = sim + B_SZ * B_SZ;           // 1024*512
    float* v    = u + B_SZ * ZH;               // 1024*512
    float* g    = v + B_SZ * ZH;               // 1024*512
    float* W1T  = g + B_SZ * ZH;               // 512*576
    float* ha   = W1T + 512 * 576;             // 1024*64
    float* pw   = ha + B_SZ * AH;              // 1024*4
    unsigned* cnt = (unsigned*)(pw + B_SZ * 4);

    prep_kernel<<<88, 256, 0, stream>>>(W1, actions, Wa, ba, W1T, ha, cnt);
    mm_kernel<<<640, 256, 0, stream>>>(z, z_next, z_next_hat, W1T, b1, W2, ha,
                                       sim, u, v, g);
    row2_kernel<<<1024, 256, 0, stream>>>(sim, u, v, g, z, z_next, b2, pw, cnt, out);
}